// Round 3
// baseline (887.696 us; speedup 1.0000x reference)
//
#include <hip/hip_runtime.h>

#define STEPS 16
#define NPAIR 1024   // H/2
#define RWS   8      // rows per workgroup
#define PPT   4      // pairs per thread
#define TPB   256    // threads per block (NPAIR / PPT)

// Coefficient tables in d_ws (written by eunn_build each launch):
//  TAc [STEPS*NPAIR] float4 : layer-A complex coefs {ce_re, ce_im, ne_re, ne_im} for pair i
//  TAr [STEPS*NPAIR] float2 : layer-A real coefs {ct0, st0} for pair i
//  TBc [STEPS*NPAIR] float4 : layer-B complex coefs for boundary i (pairs i,i+1)
//  TBr2[STEPS*NPAIR] float2 : layer-B real coefs of boundary i-1, PRE-SHIFTED to index i

__global__ __launch_bounds__(256)
void eunn_build(const float* __restrict__ ang,
                float4* __restrict__ TAc, float2* __restrict__ TAr,
                float4* __restrict__ TBc, float2* __restrict__ TBr2) {
    int idx = blockIdx.x * blockDim.x + threadIdx.x;   // 0 .. STEPS*NPAIR-1
    if (idx >= STEPS * NPAIR) return;
    int s = idx >> 10;          // step
    int i = idx & (NPAIR - 1);  // pair / boundary index
    // phi = angles[2i, 2s+l], theta = angles[2i+1, 2s+l]; angles stride 32
    float phi0 = ang[(2 * i) * 32 + 2 * s];
    float th0  = ang[(2 * i + 1) * 32 + 2 * s];
    float phi1 = ang[(2 * i) * 32 + 2 * s + 1];
    float th1  = ang[(2 * i + 1) * 32 + 2 * s + 1];
    float sp0, cp0, st0, ct0, sp1, cp1, st1, ct1;
    sincosf(phi0, &sp0, &cp0);
    sincosf(th0,  &st0, &ct0);
    sincosf(phi1, &sp1, &cp1);
    sincosf(th1,  &st1, &ct1);
    TAc[idx] = make_float4(cp0 * ct0, sp0 * ct0, -cp0 * st0, -sp0 * st0);
    TAr[idx] = make_float2(ct0, st0);
    TBc[idx] = make_float4(cp1 * ct1, sp1 * ct1, -cp1 * st1, -sp1 * st1);
    int ish = (i + 1) & (NPAIR - 1);          // boundary i real coefs -> slot i+1
    TBr2[s * NPAIR + ish] = make_float2(ct1, st1);
}

// Main kernel: each WG processes RWS rows. Thread t owns pairs [PPT*t .. PPT*t+PPT-1]
// (contiguous), i.e. complex positions 2*PPT*t .. 2*PPT*t+2*PPT-1, stored as
// X[r][j] = {x0.re, x0.im, x1.re, x1.im} of pair PPT*t+j.
// Layer A: local. Layer B (odd pairing): internal boundaries local; edges via LDS.
__global__ __launch_bounds__(TPB, 2)
void eunn_main(const float4* __restrict__ xin, float4* __restrict__ xout,
               const float4* __restrict__ TAc, const float2* __restrict__ TAr,
               const float4* __restrict__ TBc, const float2* __restrict__ TBr2) {
    __shared__ float2 l0[RWS][TPB];   // x0 of thread's first pair (post layer A)
    __shared__ float2 l1[RWS][TPB];   // x1 of thread's last pair  (post layer A)

    const int t = threadIdx.x;
    // float4 units: one row = NPAIR float4s
    const long base = (long)blockIdx.x * RWS * NPAIR + t * PPT;

    float4 X[RWS][PPT];
#pragma unroll
    for (int r = 0; r < RWS; ++r)
#pragma unroll
        for (int j = 0; j < PPT; ++j)
            X[r][j] = xin[base + (long)r * NPAIR + j];

    const int tp = (t + 1) & (TPB - 1);
    const int tm = (t - 1) & (TPB - 1);

    for (int s = 0; s < STEPS; ++s) {
        float4 ac[PPT]; float2 ar[PPT]; float4 bc[PPT]; float2 br[PPT];
        const int cb = s * NPAIR + t * PPT;
#pragma unroll
        for (int j = 0; j < PPT; ++j) {
            ac[j] = TAc[cb + j];
            ar[j] = TAr[cb + j];
            bc[j] = TBc[cb + j];
            br[j] = TBr2[cb + j];
        }

        // ---- Layer A: pair (2p, 2p+1), fully thread-local ----
#pragma unroll
        for (int r = 0; r < RWS; ++r) {
#pragma unroll
            for (int j = 0; j < PPT; ++j) {
                float x0r = X[r][j].x, x0i = X[r][j].y;
                float x1r = X[r][j].z, x1i = X[r][j].w;
                float y0r = x0r * ac[j].x - x0i * ac[j].y + x1r * ac[j].z - x1i * ac[j].w;
                float y0i = x0r * ac[j].y + x0i * ac[j].x + x1r * ac[j].w + x1i * ac[j].z;
                float y1r = ar[j].x * x1r + ar[j].y * x0r;
                float y1i = ar[j].x * x1i + ar[j].y * x0i;
                X[r][j] = make_float4(y0r, y0i, y1r, y1i);
            }
            l0[r][t] = make_float2(X[r][0].x, X[r][0].y);
            l1[r][t] = make_float2(X[r][PPT - 1].z, X[r][PPT - 1].w);
        }
        __syncthreads();

        // ---- Layer B: boundary p couples (x1 of pair p, x0 of pair p+1) ----
#pragma unroll
        for (int r = 0; r < RWS; ++r) {
            float2 rx0 = l0[r][tp];   // old x0 of pair PPT*t+PPT (right neighbor)
            float2 lx1 = l1[r][tm];   // old x1 of pair PPT*t-1   (left neighbor)

            // new x0 of first owned pair: boundary PPT*t-1 real coefs (pre-shifted into br[0])
            float nx0r = br[0].x * X[r][0].x + br[0].y * lx1.x;
            float nx0i = br[0].x * X[r][0].y + br[0].y * lx1.y;

            // internal boundaries j = PPT*t+j for j=0..PPT-2
#pragma unroll
            for (int j = 0; j < PPT - 1; ++j) {
                float x1r = X[r][j].z,     x1i = X[r][j].w;
                float x0r = X[r][j + 1].x, x0i = X[r][j + 1].y;
                X[r][j].z     = x1r * bc[j].x - x1i * bc[j].y + x0r * bc[j].z - x0i * bc[j].w;
                X[r][j].w     = x1r * bc[j].y + x1i * bc[j].x + x0r * bc[j].w + x0i * bc[j].z;
                X[r][j + 1].x = br[j + 1].x * x0r + br[j + 1].y * x1r;
                X[r][j + 1].y = br[j + 1].x * x0i + br[j + 1].y * x1i;
            }
            // edge boundary: x1 of last owned pair, partner = right neighbor's old x0
            {
                float x1r = X[r][PPT - 1].z, x1i = X[r][PPT - 1].w;
                X[r][PPT - 1].z = x1r * bc[PPT - 1].x - x1i * bc[PPT - 1].y
                                + rx0.x * bc[PPT - 1].z - rx0.y * bc[PPT - 1].w;
                X[r][PPT - 1].w = x1r * bc[PPT - 1].y + x1i * bc[PPT - 1].x
                                + rx0.x * bc[PPT - 1].w + rx0.y * bc[PPT - 1].z;
            }
            X[r][0].x = nx0r;
            X[r][0].y = nx0i;
        }
        __syncthreads();
    }

#pragma unroll
    for (int r = 0; r < RWS; ++r)
#pragma unroll
        for (int j = 0; j < PPT; ++j)
            xout[base + (long)r * NPAIR + j] = X[r][j];
}

extern "C" void kernel_launch(void* const* d_in, const int* in_sizes, int n_in,
                              void* d_out, int out_size, void* d_ws, size_t ws_size,
                              hipStream_t stream) {
    const float* x   = (const float*)d_in[0];   // (8192, 2048, 2) f32
    const float* ang = (const float*)d_in[1];   // (2048, 32) f32
    float* out = (float*)d_out;

    char* ws = (char*)d_ws;
    float4* TAc  = (float4*)(ws);                 // 256 KB
    float4* TBc  = (float4*)(ws + 256 * 1024);    // 256 KB
    float2* TAr  = (float2*)(ws + 512 * 1024);    // 128 KB
    float2* TBr2 = (float2*)(ws + 640 * 1024);    // 128 KB  (total 768 KB)

    eunn_build<<<(STEPS * NPAIR + 255) / 256, 256, 0, stream>>>(ang, TAc, TAr, TBc, TBr2);

    const int B = 8192;
    eunn_main<<<B / RWS, TPB, 0, stream>>>((const float4*)x, (float4*)out,
                                           TAc, TAr, TBc, TBr2);
}

// Round 4
// 353.692 us; speedup vs baseline: 2.5098x; 2.5098x over previous
//
#include <hip/hip_runtime.h>

#define STEPS 16
#define NPAIR 1024   // H/2
#define RWS   4      // rows per workgroup
#define PPT   2      // pairs per thread
#define TPB   512    // threads per block (NPAIR / PPT)

// Coefficient tables in d_ws (written by eunn_build each launch):
//  TAc [STEPS*NPAIR] float4 : layer-A complex coefs {ce_re, ce_im, ne_re, ne_im} for pair i
//  TAr [STEPS*NPAIR] float2 : layer-A real coefs {ct0, st0} for pair i
//  TBc [STEPS*NPAIR] float4 : layer-B complex coefs for boundary i (pairs i,i+1)
//  TBr2[STEPS*NPAIR] float2 : layer-B real coefs of boundary i-1, PRE-SHIFTED to index i

__global__ __launch_bounds__(256)
void eunn_build(const float* __restrict__ ang,
                float4* __restrict__ TAc, float2* __restrict__ TAr,
                float4* __restrict__ TBc, float2* __restrict__ TBr2) {
    int idx = blockIdx.x * blockDim.x + threadIdx.x;   // 0 .. STEPS*NPAIR-1
    if (idx >= STEPS * NPAIR) return;
    int s = idx >> 10;          // step
    int i = idx & (NPAIR - 1);  // pair / boundary index
    float phi0 = ang[(2 * i) * 32 + 2 * s];
    float th0  = ang[(2 * i + 1) * 32 + 2 * s];
    float phi1 = ang[(2 * i) * 32 + 2 * s + 1];
    float th1  = ang[(2 * i + 1) * 32 + 2 * s + 1];
    float sp0, cp0, st0, ct0, sp1, cp1, st1, ct1;
    sincosf(phi0, &sp0, &cp0);
    sincosf(th0,  &st0, &ct0);
    sincosf(phi1, &sp1, &cp1);
    sincosf(th1,  &st1, &ct1);
    TAc[idx] = make_float4(cp0 * ct0, sp0 * ct0, -cp0 * st0, -sp0 * st0);
    TAr[idx] = make_float2(ct0, st0);
    TBc[idx] = make_float4(cp1 * ct1, sp1 * ct1, -cp1 * st1, -sp1 * st1);
    int ish = (i + 1) & (NPAIR - 1);          // boundary i real coefs -> slot i+1
    TBr2[s * NPAIR + ish] = make_float2(ct1, st1);
}

// Each WG processes RWS rows; thread t owns pairs [PPT*t, PPT*t+1] (contiguous).
// X[r][j] = {x0.re, x0.im, x1.re, x1.im} of pair PPT*t+j.
// Layer A thread-local; layer B internal boundary local, chunk edges via LDS.
// Per-thread live state kept ~100 VGPR so nothing spills (round-3 lesson:
// RWS=8/PPT=4 spilled X to scratch -> 3.2 GB extra HBM traffic).
__global__ __launch_bounds__(TPB, 4)
void eunn_main(const float4* __restrict__ xin, float4* __restrict__ xout,
               const float4* __restrict__ TAc, const float2* __restrict__ TAr,
               const float4* __restrict__ TBc, const float2* __restrict__ TBr2) {
    __shared__ float2 l0[RWS][TPB];   // x0 of thread's first pair (post layer A)
    __shared__ float2 l1[RWS][TPB];   // x1 of thread's last pair  (post layer A)

    const int t = threadIdx.x;
    const long base = (long)blockIdx.x * RWS * NPAIR + t * PPT;  // float4 units

    float4 X[RWS][PPT];
#pragma unroll
    for (int r = 0; r < RWS; ++r)
#pragma unroll
        for (int j = 0; j < PPT; ++j)
            X[r][j] = xin[base + (long)r * NPAIR + j];

    const int tp = (t + 1) & (TPB - 1);
    const int tm = (t - 1) & (TPB - 1);

#pragma unroll 1
    for (int s = 0; s < STEPS; ++s) {
        float4 ac[PPT]; float2 ar[PPT]; float4 bc[PPT]; float2 br[PPT];
        const int cb = s * NPAIR + t * PPT;
#pragma unroll
        for (int j = 0; j < PPT; ++j) {
            ac[j] = TAc[cb + j];
            ar[j] = TAr[cb + j];
            bc[j] = TBc[cb + j];
            br[j] = TBr2[cb + j];
        }

        // ---- Layer A: pair (2p, 2p+1), fully thread-local ----
#pragma unroll
        for (int r = 0; r < RWS; ++r) {
#pragma unroll
            for (int j = 0; j < PPT; ++j) {
                float x0r = X[r][j].x, x0i = X[r][j].y;
                float x1r = X[r][j].z, x1i = X[r][j].w;
                float y0r = x0r * ac[j].x - x0i * ac[j].y + x1r * ac[j].z - x1i * ac[j].w;
                float y0i = x0r * ac[j].y + x0i * ac[j].x + x1r * ac[j].w + x1i * ac[j].z;
                float y1r = ar[j].x * x1r + ar[j].y * x0r;
                float y1i = ar[j].x * x1i + ar[j].y * x0i;
                X[r][j] = make_float4(y0r, y0i, y1r, y1i);
            }
            l0[r][t] = make_float2(X[r][0].x, X[r][0].y);
            l1[r][t] = make_float2(X[r][PPT - 1].z, X[r][PPT - 1].w);
        }
        __syncthreads();

        // ---- Layer B: boundary p couples (x1 of pair p, x0 of pair p+1) ----
#pragma unroll
        for (int r = 0; r < RWS; ++r) {
            float2 rx0 = l0[r][tp];   // old x0 of pair PPT*t+PPT (right neighbor)
            float2 lx1 = l1[r][tm];   // old x1 of pair PPT*t-1   (left neighbor)

            // new x0 of first owned pair: boundary PPT*t-1 coefs (pre-shifted into br[0])
            float nx0r = br[0].x * X[r][0].x + br[0].y * lx1.x;
            float nx0i = br[0].x * X[r][0].y + br[0].y * lx1.y;

#pragma unroll
            for (int j = 0; j < PPT - 1; ++j) {
                float x1r = X[r][j].z,     x1i = X[r][j].w;
                float x0r = X[r][j + 1].x, x0i = X[r][j + 1].y;
                X[r][j].z     = x1r * bc[j].x - x1i * bc[j].y + x0r * bc[j].z - x0i * bc[j].w;
                X[r][j].w     = x1r * bc[j].y + x1i * bc[j].x + x0r * bc[j].w + x0i * bc[j].z;
                X[r][j + 1].x = br[j + 1].x * x0r + br[j + 1].y * x1r;
                X[r][j + 1].y = br[j + 1].x * x0i + br[j + 1].y * x1i;
            }
            {
                float x1r = X[r][PPT - 1].z, x1i = X[r][PPT - 1].w;
                X[r][PPT - 1].z = x1r * bc[PPT - 1].x - x1i * bc[PPT - 1].y
                                + rx0.x * bc[PPT - 1].z - rx0.y * bc[PPT - 1].w;
                X[r][PPT - 1].w = x1r * bc[PPT - 1].y + x1i * bc[PPT - 1].x
                                + rx0.x * bc[PPT - 1].w + rx0.y * bc[PPT - 1].z;
            }
            X[r][0].x = nx0r;
            X[r][0].y = nx0i;
        }
        __syncthreads();
    }

#pragma unroll
    for (int r = 0; r < RWS; ++r)
#pragma unroll
        for (int j = 0; j < PPT; ++j)
            xout[base + (long)r * NPAIR + j] = X[r][j];
}

extern "C" void kernel_launch(void* const* d_in, const int* in_sizes, int n_in,
                              void* d_out, int out_size, void* d_ws, size_t ws_size,
                              hipStream_t stream) {
    const float* x   = (const float*)d_in[0];   // (8192, 2048, 2) f32
    const float* ang = (const float*)d_in[1];   // (2048, 32) f32
    float* out = (float*)d_out;

    char* ws = (char*)d_ws;
    float4* TAc  = (float4*)(ws);                 // 256 KB
    float4* TBc  = (float4*)(ws + 256 * 1024);    // 256 KB
    float2* TAr  = (float2*)(ws + 512 * 1024);    // 128 KB
    float2* TBr2 = (float2*)(ws + 640 * 1024);    // 128 KB  (total 768 KB)

    eunn_build<<<(STEPS * NPAIR + 255) / 256, 256, 0, stream>>>(ang, TAc, TAr, TBc, TBr2);

    const int B = 8192;
    eunn_main<<<B / RWS, TPB, 0, stream>>>((const float4*)x, (float4*)out,
                                           TAc, TAr, TBc, TBr2);
}